// Round 3
// baseline (386.172 us; speedup 1.0000x reference)
//
#include <hip/hip_runtime.h>
#include <hip/hip_bf16.h>

// Problem dims (compile-time)
#define SDIM 512   // SEQDIM
#define EDIM 512   // EMBED_DIM
#define LDIM 384   // VFEAT_LEN
#define DDIM 384   // VFEAT_DIM

typedef __attribute__((ext_vector_type(4))) float float4v;

// ---------------------------------------------------------------------------
// Kernel 1: t[e][l] = tanh( sum_k wv[e][k]*v[k][l] + gh[e] ),  gh = wg @ h
// Inputs are FLOAT32. Grid: EDIM blocks x 256 threads, one block per row e.
// ---------------------------------------------------------------------------
__global__ __launch_bounds__(256) void k_tanh_s(
    const float* __restrict__ h, const float* __restrict__ v,
    const float* __restrict__ wv, const float* __restrict__ wg,
    float* __restrict__ t)
{
    const int e   = blockIdx.x;
    const int tid = threadIdx.x;
    __shared__ float wvrow[DDIM];
    __shared__ float red[4];

    // gh[e] = dot(wg[e,:], h)  (K = 512)
    float acc = 0.f;
    for (int k = tid; k < SDIM; k += 256)
        acc += wg[e * SDIM + k] * h[k];
    for (int off = 32; off > 0; off >>= 1)
        acc += __shfl_down(acc, off, 64);
    if ((tid & 63) == 0) red[tid >> 6] = acc;

    // stage wv row in LDS
    for (int k = tid; k < DDIM; k += 256)
        wvrow[k] = wv[e * DDIM + k];
    __syncthreads();

    const float gh = red[0] + red[1] + red[2] + red[3];

    for (int l = tid; l < LDIM; l += 256) {
        float s = gh;
        #pragma unroll 4
        for (int k = 0; k < DDIM; ++k)
            s += wvrow[k] * v[k * LDIM + l];   // coalesced across lanes in l
        t[e * LDIM + l] = tanhf(s);
    }
}

// ---------------------------------------------------------------------------
// Kernel 2: z[r][c] = sum_e wh[r][e] * t[e][c]; alpha[r][:] = softmax(z[r][:])
// Grid: LDIM blocks x 256 threads. One block per row r.
// ---------------------------------------------------------------------------
__global__ __launch_bounds__(256) void k_softmax(
    const float* __restrict__ wh, const float* __restrict__ t,
    float* __restrict__ alpha)
{
    const int r   = blockIdx.x;
    const int tid = threadIdx.x;
    __shared__ float whrow[EDIM];
    __shared__ float zrow[LDIM];
    __shared__ float red[4];

    for (int e2 = tid; e2 < EDIM; e2 += 256)
        whrow[e2] = wh[r * EDIM + e2];
    __syncthreads();

    for (int c = tid; c < LDIM; c += 256) {
        float z = 0.f;
        #pragma unroll 4
        for (int e2 = 0; e2 < EDIM; ++e2)
            z += whrow[e2] * t[e2 * LDIM + c];      // coalesced across lanes in c
        zrow[c] = z;
    }
    __syncthreads();

    // row max
    float m = -INFINITY;
    for (int c = tid; c < LDIM; c += 256) m = fmaxf(m, zrow[c]);
    for (int off = 32; off > 0; off >>= 1)
        m = fmaxf(m, __shfl_down(m, off, 64));
    if ((tid & 63) == 0) red[tid >> 6] = m;
    __syncthreads();
    m = fmaxf(fmaxf(red[0], red[1]), fmaxf(red[2], red[3]));
    __syncthreads();   // red[] about to be reused

    // exp and row sum
    float sum = 0.f;
    for (int c = tid; c < LDIM; c += 256) {
        float ez = expf(zrow[c] - m);
        zrow[c] = ez;
        sum += ez;
    }
    for (int off = 32; off > 0; off >>= 1)
        sum += __shfl_down(sum, off, 64);
    if ((tid & 63) == 0) red[tid >> 6] = sum;
    __syncthreads();
    const float rs = 1.f / (red[0] + red[1] + red[2] + red[3]);

    for (int c = tid; c < LDIM; c += 256)
        alpha[r * LDIM + c] = zrow[c] * rs;
}

// ---------------------------------------------------------------------------
// Kernel 3: out[i][j][k] = v[j][k] * alpha[i][j]
// out is FLOAT32 (384^3 * 4 B = 226.5 MB of writes — the structural floor).
// Each thread writes one float4 (16 B) per iteration.
// ---------------------------------------------------------------------------
__global__ __launch_bounds__(256) void k_out(
    const float* __restrict__ v, const float* __restrict__ alpha,
    float* __restrict__ out)
{
    constexpr int VPR = LDIM / 4;            // 96 float4 vectors per v row
    constexpr int NV  = LDIM * DDIM * VPR;   // 14,155,776 total output vectors
    const int stride = gridDim.x * 256;

    for (int g = blockIdx.x * 256 + threadIdx.x; g < NV; g += stride) {
        const int i   = g / (DDIM * VPR);    // 36864 per i
        const int rem = g - i * (DDIM * VPR);
        const int j   = rem / VPR;
        const int k4  = rem - j * VPR;

        const float a = alpha[i * DDIM + j];
        float4v vv = *(const float4v*)(v + j * LDIM + k4 * 4);
        vv *= a;
        ((float4v*)out)[g] = vv;
    }
}

// ---------------------------------------------------------------------------
extern "C" void kernel_launch(void* const* d_in, const int* in_sizes, int n_in,
                              void* d_out, int out_size, void* d_ws, size_t ws_size,
                              hipStream_t stream)
{
    const float* h  = (const float*)d_in[0];   // (512, 1)   f32
    const float* v  = (const float*)d_in[1];   // (384, 384) f32
    const float* wh = (const float*)d_in[2];   // (384, 512) f32
    const float* wv = (const float*)d_in[3];   // (512, 384) f32
    const float* wg = (const float*)d_in[4];   // (512, 512) f32
    float* out = (float*)d_out;                // (384, 384, 384) f32

    float* t     = (float*)d_ws;               // (512, 384) f32 scratch
    float* alpha = t + EDIM * LDIM;            // (384, 384) f32 scratch

    k_tanh_s <<<EDIM, 256, 0, stream>>>(h, v, wv, wg, t);
    k_softmax<<<LDIM, 256, 0, stream>>>(wh, t, alpha);
    // 6912 blocks * 256 threads * 8 vec4/thread == 14,155,776 vectors exactly
    k_out    <<<6912, 256, 0, stream>>>(v, alpha, out);
}

// Round 4
// 300.757 us; speedup vs baseline: 1.2840x; 1.2840x over previous
//
#include <hip/hip_runtime.h>
#include <hip/hip_bf16.h>

// Problem dims (compile-time)
#define SDIM 512   // SEQDIM
#define EDIM 512   // EMBED_DIM
#define LDIM 384   // VFEAT_LEN
#define DDIM 384   // VFEAT_DIM

typedef __attribute__((ext_vector_type(4))) float float4v;

// ---------------------------------------------------------------------------
// Kernel 1: t[e][l] = tanh( sum_k wv[e][k]*v[k][l] + gh[e] ),  gh = wg @ h
// e-tiled x2: 256 blocks, each computes rows (2b, 2b+1). Shares the v loads
// between both rows (halves L2 traffic) and gives 4 independent FMA chains.
// ---------------------------------------------------------------------------
__global__ __launch_bounds__(256) void k_tanh_s(
    const float* __restrict__ h, const float* __restrict__ v,
    const float* __restrict__ wv, const float* __restrict__ wg,
    float* __restrict__ t)
{
    const int e0  = blockIdx.x * 2;
    const int tid = threadIdx.x;
    __shared__ float wvs[2 * DDIM];   // two wv rows
    __shared__ float red[2][2];

    // gh for both rows: waves 0-1 -> row 0, waves 2-3 -> row 1
    {
        const int row  = tid >> 7;       // 0 or 1
        const int l128 = tid & 127;
        float acc = 0.f;
        for (int k = l128; k < SDIM; k += 128)
            acc += wg[(e0 + row) * SDIM + k] * h[k];
        for (int off = 32; off > 0; off >>= 1)
            acc += __shfl_down(acc, off, 64);
        if ((tid & 63) == 0) red[row][(tid >> 6) & 1] = acc;
    }

    // stage both wv rows in LDS
    for (int k = tid; k < 2 * DDIM; k += 256)
        wvs[k] = wv[e0 * DDIM + k];
    __syncthreads();

    const float gh0 = red[0][0] + red[0][1];
    const float gh1 = red[1][0] + red[1][1];

    for (int l = tid; l < LDIM; l += 256) {
        float a0 = 0.f, a1 = 0.f, b0 = 0.f, b1 = 0.f;
        const float* vp = v + l;
        #pragma unroll 8
        for (int k = 0; k < DDIM; k += 2) {
            const float v0 = vp[k * LDIM];
            const float v1 = vp[(k + 1) * LDIM];
            a0 += wvs[k]        * v0;
            a1 += wvs[k + 1]    * v1;
            b0 += wvs[DDIM + k]     * v0;
            b1 += wvs[DDIM + k + 1] * v1;
        }
        t[e0 * LDIM + l]       = tanhf((a0 + a1) + gh0);
        t[(e0 + 1) * LDIM + l] = tanhf((b0 + b1) + gh1);
    }
}

// ---------------------------------------------------------------------------
// Kernel 2: z[r][c] = sum_e wh[r][e] * t[e][c]; alpha[r][:] = softmax(z[r][:])
// r-tiled x2: 192 blocks, each handles rows (2b, 2b+1).
// ---------------------------------------------------------------------------
__global__ __launch_bounds__(256) void k_softmax(
    const float* __restrict__ wh, const float* __restrict__ t,
    float* __restrict__ alpha)
{
    const int r0  = blockIdx.x * 2;
    const int tid = threadIdx.x;
    __shared__ float whs[2 * EDIM];    // two wh rows
    __shared__ float zr[2][LDIM];
    __shared__ float redm[2][2];
    __shared__ float reds[2][2];

    for (int e = tid; e < 2 * EDIM; e += 256)
        whs[e] = wh[r0 * EDIM + e];
    __syncthreads();

    for (int c = tid; c < LDIM; c += 256) {
        float z00 = 0.f, z01 = 0.f, z10 = 0.f, z11 = 0.f;
        #pragma unroll 8
        for (int e = 0; e < EDIM; e += 2) {
            const float t0 = t[e * LDIM + c];
            const float t1 = t[(e + 1) * LDIM + c];
            z00 += whs[e]     * t0;
            z01 += whs[e + 1] * t1;
            z10 += whs[EDIM + e]     * t0;
            z11 += whs[EDIM + e + 1] * t1;
        }
        zr[0][c] = z00 + z01;
        zr[1][c] = z10 + z11;
    }
    __syncthreads();

    // softmax: waves 0-1 -> row 0, waves 2-3 -> row 1
    const int row = tid >> 7;
    const int l1  = tid & 127;

    float m = -INFINITY;
    for (int c = l1; c < LDIM; c += 128) m = fmaxf(m, zr[row][c]);
    for (int off = 32; off > 0; off >>= 1)
        m = fmaxf(m, __shfl_down(m, off, 64));
    if ((tid & 63) == 0) redm[row][(tid >> 6) & 1] = m;
    __syncthreads();
    m = fmaxf(redm[row][0], redm[row][1]);

    float sum = 0.f;
    for (int c = l1; c < LDIM; c += 128) {
        const float ez = expf(zr[row][c] - m);
        zr[row][c] = ez;
        sum += ez;
    }
    for (int off = 32; off > 0; off >>= 1)
        sum += __shfl_down(sum, off, 64);
    if ((tid & 63) == 0) reds[row][(tid >> 6) & 1] = sum;
    __syncthreads();
    const float rs = 1.f / (reds[row][0] + reds[row][1]);

    for (int c = l1; c < LDIM; c += 128)
        alpha[(r0 + row) * LDIM + c] = zr[row][c] * rs;
}

// ---------------------------------------------------------------------------
// Kernel 3: out[i][j][k] = v[j][k] * alpha[i][j]   (226.5 MB f32 writes)
// 768 blocks: 2 per i-slice. Alpha row in LDS; one magic-div by 96 per vec4;
// nontemporal float4 stores (streaming output, keep L2 clean).
// ---------------------------------------------------------------------------
__global__ __launch_bounds__(256) void k_out(
    const float* __restrict__ v, const float* __restrict__ alpha,
    float* __restrict__ out)
{
    constexpr int VPS  = (LDIM * DDIM) / 4;  // 36864 vec4 per i-slice
    constexpr int HALF = VPS / 2;            // 18432
    const int i = blockIdx.x >> 1;
    const int h = blockIdx.x & 1;

    __shared__ float arow[DDIM];
    for (int j = threadIdx.x; j < DDIM; j += 256)
        arow[j] = alpha[i * DDIM + j];
    __syncthreads();

    const float4v* v4 = (const float4v*)v;
    float4v* o4 = (float4v*)out + (size_t)i * VPS;
    const int base = h * HALF;

    #pragma unroll 4
    for (int it = 0; it < HALF / 256; ++it) {       // 72 iterations
        const int idx = base + it * 256 + (int)threadIdx.x;
        const int j   = idx / 96;                   // 96 vec4 per v row
        const float a = arow[j];
        float4v vv = v4[idx];
        vv *= a;
        __builtin_nontemporal_store(vv, o4 + idx);
    }
}

// ---------------------------------------------------------------------------
extern "C" void kernel_launch(void* const* d_in, const int* in_sizes, int n_in,
                              void* d_out, int out_size, void* d_ws, size_t ws_size,
                              hipStream_t stream)
{
    const float* h  = (const float*)d_in[0];   // (512, 1)   f32
    const float* v  = (const float*)d_in[1];   // (384, 384) f32
    const float* wh = (const float*)d_in[2];   // (384, 512) f32
    const float* wv = (const float*)d_in[3];   // (512, 384) f32
    const float* wg = (const float*)d_in[4];   // (512, 512) f32
    float* out = (float*)d_out;                // (384, 384, 384) f32

    float* t     = (float*)d_ws;               // (512, 384) f32 scratch
    float* alpha = t + EDIM * LDIM;            // (384, 384) f32 scratch

    k_tanh_s <<<EDIM / 2, 256, 0, stream>>>(h, v, wv, wg, t);
    k_softmax<<<LDIM / 2, 256, 0, stream>>>(wh, t, alpha);
    k_out    <<<2 * LDIM, 256, 0, stream>>>(v, alpha, out);
}